// Round 1
// baseline (1177.446 us; speedup 1.0000x reference)
//
#include <hip/hip_runtime.h>

#define N_SYS 16
#define EPS_F 1e-12f
#define ACC_ELEMS (N_SYS * 64)   // 1024 sum slots
#define WS_FLOATS (ACC_ELEMS + N_SYS)

// ---------------------------------------------------------------------------
// Kernel 0: zero the workspace (sums[16][64] + counts[16])
// ---------------------------------------------------------------------------
__global__ void ws_init_kernel(float* __restrict__ ws) {
    int t = blockIdx.x * blockDim.x + threadIdx.x;
    if (t < WS_FLOATS) ws[t] = 0.0f;
}

// ---------------------------------------------------------------------------
// Kernel 1: normalize rows + segment-sum into ws via per-block LDS accum.
// 16 lanes per row; each lane owns 4 dims (one float4 load = 16 B/lane).
// ---------------------------------------------------------------------------
__global__ __launch_bounds__(256) void accum_kernel(
    const float4* __restrict__ out4,      // [N][16] float4 view of [N][64] f32
    const int*    __restrict__ system,    // [N]
    float*        __restrict__ ws,        // sums[16][64] then counts[16]
    int N)
{
    __shared__ float acc[ACC_ELEMS];      // [sys][dim]
    __shared__ float cnt[N_SYS];

    for (int i = threadIdx.x; i < ACC_ELEMS; i += 256) acc[i] = 0.0f;
    if (threadIdx.x < N_SYS) cnt[threadIdx.x] = 0.0f;
    __syncthreads();

    const int s = threadIdx.x & 15;       // dim-group within row (4 dims)
    const int r = threadIdx.x >> 4;       // row slot within block (0..15)
    const long rowStride = (long)gridDim.x * 16;

    for (long row = (long)blockIdx.x * 16 + r; row < N; row += rowStride) {
        float4 v = out4[row * 16 + s];
        float ss = v.x * v.x + v.y * v.y + v.z * v.z + v.w * v.w;
        // reduce sum-of-squares across the 16-lane row group
        ss += __shfl_xor(ss, 8, 16);
        ss += __shfl_xor(ss, 4, 16);
        ss += __shfl_xor(ss, 2, 16);
        ss += __shfl_xor(ss, 1, 16);
        float scale = 1.0f / fmaxf(sqrtf(ss), EPS_F);

        int sys = system[row];
        float* a = &acc[sys * 64 + s * 4];
        atomicAdd(a + 0, v.x * scale);
        atomicAdd(a + 1, v.y * scale);
        atomicAdd(a + 2, v.z * scale);
        atomicAdd(a + 3, v.w * scale);
        if (s == 0) atomicAdd(&cnt[sys], 1.0f);
    }
    __syncthreads();

    // flush block partials to global
    for (int i = threadIdx.x; i < ACC_ELEMS; i += 256)
        atomicAdd(&ws[i], acc[i]);
    if (threadIdx.x < N_SYS)
        atomicAdd(&ws[ACC_ELEMS + threadIdx.x], cnt[threadIdx.x]);
}

// ---------------------------------------------------------------------------
// Kernel 2: means = sums/counts; dist[i][j] = 0.5 - 0.5 * (m_i . m_j), 0 diag
// One thread per (i,j) pair (256 threads).
// ---------------------------------------------------------------------------
__global__ __launch_bounds__(256) void finalize_kernel(
    const float* __restrict__ ws, float* __restrict__ dst)
{
    __shared__ float m[ACC_ELEMS];
    int t = threadIdx.x;
    for (int i = t; i < ACC_ELEMS; i += 256) {
        float c = ws[ACC_ELEMS + (i >> 6)];
        m[i] = ws[i] / c;
    }
    __syncthreads();

    int i = t >> 4, j = t & 15;
    float dot = 0.0f;
    #pragma unroll
    for (int d = 0; d < 64; ++d)
        dot += m[i * 64 + d] * m[j * 64 + d];
    dst[t] = (i == j) ? 0.0f : (0.5f - 0.5f * dot);
}

// ---------------------------------------------------------------------------
extern "C" void kernel_launch(void* const* d_in, const int* in_sizes, int n_in,
                              void* d_out, int out_size, void* d_ws, size_t ws_size,
                              hipStream_t stream) {
    const float4* out4   = (const float4*)d_in[0];
    const int*    system = (const int*)d_in[1];
    float*        ws     = (float*)d_ws;
    float*        dst    = (float*)d_out;
    int N = in_sizes[1];                  // number of rows (system has N entries)

    ws_init_kernel<<<(WS_FLOATS + 255) / 256, 256, 0, stream>>>(ws);
    accum_kernel<<<2048, 256, 0, stream>>>(out4, system, ws, N);
    finalize_kernel<<<1, 256, 0, stream>>>(ws, dst);
}